// Round 3
// baseline (685.312 us; speedup 1.0000x reference)
//
#include <hip/hip_runtime.h>
#include <math.h>

#define BATCH   32
#define HIDDEN  1152
#define FREQ    256
#define HALF    128
#define SEQLEN  4096

typedef float vf4 __attribute__((ext_vector_type(4)));   // clang vector: valid for nontemporal builtins

// ---------------------------------------------------------------------------
// Kernel 1: sinusoidal embedding + first GEMM (256 -> 1152) + tanh-GELU.
// One block per batch element, 256 threads.
// ---------------------------------------------------------------------------
__global__ __launch_bounds__(256) void k_hidden(const float* __restrict__ t,
                                                const float* __restrict__ W1,
                                                const float* __restrict__ b1,
                                                float* __restrict__ h_out) {
    __shared__ float emb[FREQ];
    const int b   = blockIdx.x;
    const int tid = threadIdx.x;
    const float tb = t[b];

    {
        const int   j    = tid & (HALF - 1);
        // exp(-ln(10000)*j/128) == exp2(-log2(10000)*j/128)
        const float freq = exp2f(-13.287712379549449f * (float)j * (1.0f / (float)HALF));
        const float arg  = tb * freq;
        emb[tid] = (tid < HALF) ? cosf(arg) : sinf(arg);
    }
    __syncthreads();

    for (int o = tid; o < HIDDEN; o += 256) {
        const float4* __restrict__ w4 = reinterpret_cast<const float4*>(W1 + (size_t)o * FREQ);
        float s0 = 0.f, s1 = 0.f, s2 = 0.f, s3 = 0.f;
#pragma unroll 8
        for (int k4 = 0; k4 < FREQ / 4; ++k4) {
            const float4 w = w4[k4];
            s0 += w.x * emb[4 * k4 + 0];
            s1 += w.y * emb[4 * k4 + 1];
            s2 += w.z * emb[4 * k4 + 2];
            s3 += w.w * emb[4 * k4 + 3];
        }
        const float x  = (s0 + s1) + (s2 + s3) + b1[o];
        const float x3 = x * x * x;
        const float g  = 0.5f * x * (1.0f + tanhf(0.7978845608028654f * (x + 0.044715f * x3)));
        h_out[b * HIDDEN + o] = g;
    }
}

// ---------------------------------------------------------------------------
// Kernel 2: second GEMM (1152 -> 1152). Grid (9, 32) x 128 threads.
// ---------------------------------------------------------------------------
__global__ __launch_bounds__(128) void k_out(const float* __restrict__ h,
                                             const float* __restrict__ W2,
                                             const float* __restrict__ b2,
                                             float* __restrict__ outv) {
    __shared__ float hs[HIDDEN];
    const int b = blockIdx.y;
    const int o = blockIdx.x * 128 + threadIdx.x;   // 9*128 == 1152 exactly

    for (int k = threadIdx.x; k < HIDDEN; k += 128)
        hs[k] = h[b * HIDDEN + k];
    __syncthreads();

    const float4* __restrict__ w4 = reinterpret_cast<const float4*>(W2 + (size_t)o * HIDDEN);
    float s0 = 0.f, s1 = 0.f, s2 = 0.f, s3 = 0.f;
#pragma unroll 4
    for (int k4 = 0; k4 < HIDDEN / 4; ++k4) {
        const float4 w = w4[k4];
        s0 += w.x * hs[4 * k4 + 0];
        s1 += w.y * hs[4 * k4 + 1];
        s2 += w.z * hs[4 * k4 + 2];
        s3 += w.w * hs[4 * k4 + 3];
    }
    outv[b * HIDDEN + o] = (s0 + s1) + (s2 + s3) + b2[o];
}

// ---------------------------------------------------------------------------
// Kernel 3: broadcast. One WAVE owns one output row (4096 f32 = 16 KB):
// value loaded ONCE into a register, then 16 unrolled, independent,
// fully-coalesced 16B nontemporal stores (1 KB per instruction per wave).
// Zero loads in the steady-state store stream.
// ---------------------------------------------------------------------------
__global__ __launch_bounds__(256) void k_bcast(const float* __restrict__ outv,
                                               vf4* __restrict__ dst) {
    const int gwave  = (blockIdx.x * 256 + threadIdx.x) >> 6;
    const int lane   = threadIdx.x & 63;
    const int nwaves = (gridDim.x * 256) >> 6;
    const int ROWS   = BATCH * HIDDEN;               // 36864

    for (int row = gwave; row < ROWS; row += nwaves) {
        const float v = outv[row];
        const vf4 val = {v, v, v, v};
        vf4* p = dst + (size_t)row * (SEQLEN / 4) + lane;
#pragma unroll
        for (int it = 0; it < (SEQLEN / 4) / 64; ++it)   // 16 stores/row/lane
            __builtin_nontemporal_store(val, p + it * 64);
    }
}

extern "C" void kernel_launch(void* const* d_in, const int* in_sizes, int n_in,
                              void* d_out, int out_size, void* d_ws, size_t ws_size,
                              hipStream_t stream) {
    const float* t  = (const float*)d_in[0];
    const float* W1 = (const float*)d_in[1];
    const float* b1 = (const float*)d_in[2];
    const float* W2 = (const float*)d_in[3];
    const float* b2 = (const float*)d_in[4];
    float* outf = (float*)d_out;

    float* h  = (float*)d_ws;            // 32*1152 f32
    float* ov = h + BATCH * HIDDEN;      // 32*1152 f32

    k_hidden<<<BATCH, 256, 0, stream>>>(t, W1, b1, h);
    k_out<<<dim3(HIDDEN / 128, BATCH), 128, 0, stream>>>(h, W2, b2, ov);
    k_bcast<<<2048, 256, 0, stream>>>(ov, (vf4*)outf);
}